// Round 16
// baseline (243.994 us; speedup 1.0000x reference)
//
#include <hip/hip_runtime.h>
#include <hip/hip_bf16.h>

// VisionAttention: S=4096, E=1280, H=16, D=80 (padded to 96 for MFMA K-steps)
// cast3->bf16 (Wqkv Q/K rows pair-interleaved; zero Qg/Kg pads) |
// GEMM1 qkv 256^2 8-phase (+bias, LDS bounce; RoPE fused on Q/K readback;
// V readback transposes to Vt sigma-permuted) |
// flash attention v9 (split-K pairs, in-register P, V direct-from-L2) |
// GEMM2 (+bias+residual, XCD swizzle)

#define S_LEN 4096
#define E_DIM 1280
#define NH 16
#define HD 80
#define HDP 96

typedef __bf16 bf16x8 __attribute__((ext_vector_type(8)));
typedef float f32x4 __attribute__((ext_vector_type(4)));

__device__ __forceinline__ short f2bf(float x) {
    __hip_bfloat16 h = __float2bfloat16(x);
    return __builtin_bit_cast(short, h);
}
__device__ __forceinline__ float bf2f(short x) {
    return __bfloat162float(__builtin_bit_cast(__hip_bfloat16, x));
}
__device__ __forceinline__ bf16x8 ldb(const short* p) {
    return *reinterpret_cast<const bf16x8*>(p);
}
// packed f32x2 -> bf16x2 (RNE), single VALU instr
__device__ __forceinline__ unsigned cvt_pk_bf16(float a, float b) {
    unsigned r;
    asm("v_cvt_pk_bf16_f32 %0, %1, %2" : "=v"(r) : "v"(a), "v"(b));
    return r;
}
// async global->LDS, 16B per lane; LDS dest = uniform base + lane*16
__device__ __forceinline__ void gload16(const void* g, void* l) {
    __builtin_amdgcn_global_load_lds(
        (const __attribute__((address_space(1))) unsigned int*)g,
        (__attribute__((address_space(3))) unsigned int*)l, 16, 0, 0);
}

// ---------------- fused cast f32 -> bf16 + pad-zero (4 segments, one launch) -------
__global__ __launch_bounds__(256) void cast3_k(const float* __restrict__ a, short* __restrict__ oa, int na4,
                                               const float* __restrict__ b, short* __restrict__ ob, int nb4,
                                               const float* __restrict__ c, short* __restrict__ oc, int nc4,
                                               short* __restrict__ Qg, short* __restrict__ Kg, int nd4) {
    int j = blockIdx.x * 256 + threadIdx.x;
    const float* src;
    short* dst;
    bool remap = false;
    if (j < na4) {
        src = a; dst = oa;
    } else {
        j -= na4;
        if (j < nb4) {
            src = b; dst = ob; remap = true;
        } else {
            j -= nb4;
            if (j < nc4) {
                src = c; dst = oc;
            } else {
                j -= nc4;
                if (j >= nd4) return;
                // pad-zero segment: nd4 = 2 * H*S*2 granules of 8 shorts
                int half = nd4 >> 1;
                short* base = (j < half) ? Qg : Kg;
                int rem = (j < half) ? j : j - half;
                int hs = rem >> 1, gp = rem & 1;
                int4 z = {0, 0, 0, 0};
                *reinterpret_cast<int4*>(&base[(size_t)hs * HDP + 80 + gp * 8]) = z;
                return;
            }
        }
    }
    float4 v = *reinterpret_cast<const float4*>(&src[j * 4]);
    int dj = j;
    if (remap) {
        int row = j / 320, c4 = j - row * 320;   // 320 float4-chunks per 1280-col row
        if (row < 2560) {                        // Q,K parts only
            int part = row / 1280;
            int loc = row - part * 1280;
            int hh = loc / 80, d = loc - hh * 80;
            int dp = (d < 40) ? 2 * d : 2 * (d - 40) + 1;
            dj = (part * 1280 + hh * 80 + dp) * 320 + c4;
        }
    }
    ushort4 o;
    o.x = (unsigned short)f2bf(v.x);
    o.y = (unsigned short)f2bf(v.y);
    o.z = (unsigned short)f2bf(v.z);
    o.w = (unsigned short)f2bf(v.w);
    *reinterpret_cast<ushort4*>(&dst[dj * 4]) = o;
}

// ---------------- GEMM1: 256x256 tile, BK=64, 8-phase counted-vmcnt ----------------
// C = A * B^T. Epilogue via bank-swizzled LDS bounce [256][256]:
//  Q/K parts: readback granule (4 RoPE pairs) -> RoPE + (Q) scale -> Qg/Kg [H][S][96]
//  V part:    column readback -> sigma-permuted transposed store to Vt [H][80][S]
__global__ __launch_bounds__(512, 2) void gemm1_256_k(
    const short* __restrict__ A, const short* __restrict__ B, const float* __restrict__ bias,
    const float* __restrict__ cosp, const float* __restrict__ sinp,
    short* __restrict__ Qg, short* __restrict__ Kg, short* __restrict__ Vt) {
    const int K = E_DIM;
    __shared__ __align__(16) short smem[65536];   // 128 KB: As | Bs, reused as bounce
#define AS_(d, kh) (smem + (d)*16384 + (kh)*8192)
#define BS_(d, kh) (smem + 32768 + (d)*16384 + (kh)*8192)
    int t = threadIdx.x;
    int lane = t & 63, w = t >> 6;
    int wr = w >> 2, wc = w & 3;
    int lr = lane & 15, lg = lane >> 4;
    int bid = blockIdx.x;
    int swz = (bid & 7) * 30 + (bid >> 3);   // 240 blocks, 240%8==0 -> bijective
    int bm = swz / 15, bn = swz % 15;
    int mb = bm * 256, nb = bn * 256;

    // staging sources: dest granule p (row=p>>2, phys=p&3) <- logical (p&3)^((p>>3)&3)
    int lgs = (t & 3) ^ ((t >> 3) & 3);
    const short* aS = A + (size_t)(mb + (t >> 2)) * K + lgs * 8;
    const short* bS = B + (size_t)(nb + (t >> 2)) * K + lgs * 8;
    const int rowStep = 128 * K;   // second load: rows +128

    // frag offsets: row r, granule lg -> r*32 + (lg ^ ((r>>1)&3))*8
    int aoff[2][4], boff[4];
#pragma unroll
    for (int mq = 0; mq < 2; mq++)
#pragma unroll
        for (int ii = 0; ii < 4; ii++) {
            int r = wr * 128 + mq * 64 + ii * 16 + lr;
            aoff[mq][ii] = r * 32 + ((lg ^ ((r >> 1) & 3)) * 8);
        }
#pragma unroll
    for (int n = 0; n < 4; n++) {
        int r = wc * 64 + n * 16 + lr;
        boff[n] = r * 32 + ((lg ^ ((r >> 1) & 3)) * 8);
    }

    f32x4 acc[8][4];
#pragma unroll
    for (int i = 0; i < 8; i++)
#pragma unroll
        for (int n = 0; n < 4; n++) acc[i][n] = (f32x4){0.f, 0.f, 0.f, 0.f};

#define STG_A(d, kh, kb2)                                              \
    {                                                                  \
        gload16(aS + (kb2) + (kh)*32, AS_(d, kh) + w * 512);           \
        gload16(aS + rowStep + (kb2) + (kh)*32, AS_(d, kh) + 4096 + w * 512); \
    }
#define STG_B(d, kh, kb2)                                              \
    {                                                                  \
        gload16(bS + (kb2) + (kh)*32, BS_(d, kh) + w * 512);           \
        gload16(bS + rowStep + (kb2) + (kh)*32, BS_(d, kh) + 4096 + w * 512); \
    }

    // prologue: tile 0, all 4 half-tiles; wait A0,B0 only
    STG_A(0, 0, 0);
    STG_B(0, 0, 0);
    STG_A(0, 1, 0);
    STG_B(0, 1, 0);
    asm volatile("s_waitcnt vmcnt(4)" ::: "memory");
    __builtin_amdgcn_s_barrier();
    asm volatile("" ::: "memory");

    for (int kb = 0; kb < K; kb += 64) {
        int d = (kb >> 6) & 1;
        int kb2 = kb + 64;
        bool more = kb2 < K;
        bf16x8 af[4], bfr[4];

        // ---- phase 1: K-half 0, M-quad 0 (8 ds_reads; stage next A0) ----
#pragma unroll
        for (int n = 0; n < 4; n++) bfr[n] = ldb(&BS_(d, 0)[boff[n]]);
#pragma unroll
        for (int ii = 0; ii < 4; ii++) af[ii] = ldb(&AS_(d, 0)[aoff[0][ii]]);
        if (more) STG_A(d ^ 1, 0, kb2);
        __builtin_amdgcn_s_barrier();
        asm volatile("s_waitcnt lgkmcnt(0)" ::: "memory");
        __builtin_amdgcn_sched_barrier(0);
        __builtin_amdgcn_s_setprio(1);
#pragma unroll
        for (int ii = 0; ii < 4; ii++)
#pragma unroll
            for (int n = 0; n < 4; n++)
                acc[ii][n] = __builtin_amdgcn_mfma_f32_16x16x32_bf16(af[ii], bfr[n], acc[ii][n], 0, 0, 0);
        __builtin_amdgcn_s_setprio(0);
        __builtin_amdgcn_s_barrier();
        asm volatile("" ::: "memory");

        // ---- phase 2: K-half 0, M-quad 1 (4 ds_reads; stage next B0; vmcnt) ----
#pragma unroll
        for (int ii = 0; ii < 4; ii++) af[ii] = ldb(&AS_(d, 0)[aoff[1][ii]]);
        if (more) {
            STG_B(d ^ 1, 0, kb2);
            asm volatile("s_waitcnt vmcnt(4)" ::: "memory");   // drain this tile's A1,B1
        } else {
            asm volatile("s_waitcnt vmcnt(0)" ::: "memory");
        }
        __builtin_amdgcn_s_barrier();
        asm volatile("s_waitcnt lgkmcnt(0)" ::: "memory");
        __builtin_amdgcn_sched_barrier(0);
        __builtin_amdgcn_s_setprio(1);
#pragma unroll
        for (int ii = 0; ii < 4; ii++)
#pragma unroll
            for (int n = 0; n < 4; n++)
                acc[4 + ii][n] = __builtin_amdgcn_mfma_f32_16x16x32_bf16(af[ii], bfr[n], acc[4 + ii][n], 0, 0, 0);
        __builtin_amdgcn_s_setprio(0);
        __builtin_amdgcn_s_barrier();
        asm volatile("" ::: "memory");

        // ---- phase 3: K-half 1, M-quad 0 (8 ds_reads; stage next A1) ----
#pragma unroll
        for (int n = 0; n < 4; n++) bfr[n] = ldb(&BS_(d, 1)[boff[n]]);
#pragma unroll
        for (int ii = 0; ii < 4; ii++) af[ii] = ldb(&AS_(d, 1)[aoff[0][ii]]);
        if (more) STG_A(d ^ 1, 1, kb2);
        __builtin_amdgcn_s_barrier();
        asm volatile("s_waitcnt lgkmcnt(0)" ::: "memory");
        __builtin_amdgcn_sched_barrier(0);
        __builtin_amdgcn_s_setprio(1);
#pragma unroll
        for (int ii = 0; ii < 4; ii++)
#pragma unroll
            for (int n = 0; n < 4; n++)
                acc[ii][n] = __builtin_amdgcn_mfma_f32_16x16x32_bf16(af[ii], bfr[n], acc[ii][n], 0, 0, 0);
        __builtin_amdgcn_s_setprio(0);
        __builtin_amdgcn_s_barrier();
        asm volatile("" ::: "memory");

        // ---- phase 4: K-half 1, M-quad 1 (4 ds_reads; stage next B1; vmcnt) ----
#pragma unroll
        for (int ii = 0; ii < 4; ii++) af[ii] = ldb(&AS_(d, 1)[aoff[1][ii]]);
        if (more) {
            STG_B(d ^ 1, 1, kb2);
            asm volatile("s_waitcnt vmcnt(4)" ::: "memory");   // drain next tile's A0,B0
        }
        __builtin_amdgcn_s_barrier();
        asm volatile("s_waitcnt lgkmcnt(0)" ::: "memory");
        __builtin_amdgcn_sched_barrier(0);
        __builtin_amdgcn_s_setprio(1);
#pragma unroll
        for (int ii = 0; ii < 4; ii++)
#pragma unroll
            for (int n = 0; n < 4; n++)
                acc[4 + ii][n] = __builtin_amdgcn_mfma_f32_16x16x32_bf16(af[ii], bfr[n], acc[4 + ii][n], 0, 0, 0);
        __builtin_amdgcn_s_setprio(0);
        __builtin_amdgcn_s_barrier();
        asm volatile("" ::: "memory");
    }
#undef STG_A
#undef STG_B

    // ---- epilogue: bias -> bank-swizzled LDS bounce -> readback ----
    int part = nb / E_DIM;   // tile never crosses q/k/v boundary (1280 % 256 == 0)
    int nloc = nb - part * E_DIM;
    if (part < 2) {
        // write with row-read-friendly swizzle: granule cg -> cg ^ ((s>>2)&3)
#pragma unroll
        for (int j = 0; j < 4; j++) {
            int c = wc * 64 + j * 16 + lr;
            int pcol = nloc + c;
            int hh = pcol / 80, dl = pcol - hh * 80;
            float bv = bias[part * E_DIM + hh * 80 + ((dl & 1) ? (dl >> 1) + 40 : (dl >> 1))];
            int cw = c & 7, cg = c >> 3;
#pragma unroll
            for (int i = 0; i < 8; i++) {
#pragma unroll
                for (int r = 0; r < 4; r++) {
                    int s = wr * 128 + (i >> 2) * 64 + (i & 3) * 16 + lg * 4 + r;
                    smem[s * 256 + (((cg ^ ((s >> 2) & 3)) << 3) | cw)] = f2bf(acc[i][j][r] + bv);
                }
            }
        }
        __syncthreads();
        short* dst = part ? Kg : Qg;
        const float qs = part ? 1.0f : 0.16129849190f;   // log2(e)/sqrt(80) on Q
#pragma unroll
        for (int k = 0; k < 16; k++) {
            int g = t + k * 512;                 // 8192 granules of 16B
            int row = g >> 5, gc = g & 31;
            int pg = gc ^ ((row >> 2) & 3);
            int4 v = *reinterpret_cast<const int4*>(&smem[row * 256 + pg * 8]);
            int s = mb + row;
            int pcol = nloc + gc * 8;            // granule never crosses a head (80%8==0)
            int hh = pcol / 80;
            int dl = pcol - hh * 80;             // multiple of 8
            int i2 = dl >> 1;                    // multiple of 4
            float4 cs = *reinterpret_cast<const float4*>(&cosp[s * HD + i2]);
            float4 sn = *reinterpret_cast<const float4*>(&sinp[s * HD + i2]);
            const short* sp = reinterpret_cast<const short*>(&v);
            float f[8];
#pragma unroll
            for (int i = 0; i < 8; i++) f[i] = bf2f(sp[i]);
            float c0 = cs.x * qs, s0 = sn.x * qs;
            float c1 = cs.y * qs, s1 = sn.y * qs;
            float c2 = cs.z * qs, s2 = sn.z * qs;
            float c3 = cs.w * qs, s3 = sn.w * qs;
            uint4 pw;
            pw.x = cvt_pk_bf16(f[0] * c0 - f[1] * s0, f[1] * c0 + f[0] * s0);
            pw.y = cvt_pk_bf16(f[2] * c1 - f[3] * s1, f[3] * c1 + f[2] * s1);
            pw.z = cvt_pk_bf16(f[4] * c2 - f[5] * s2, f[5] * c2 + f[4] * s2);
            pw.w = cvt_pk_bf16(f[6] * c3 - f[7] * s3, f[7] * c3 + f[6] * s3);
            *reinterpret_cast<uint4*>(&dst[((size_t)hh * S_LEN + s) * HDP + dl]) = pw;
        }
    } else {
        // V: write with column-read-friendly swizzle: granule cg -> cg ^ vswz(s),
        // vswz(s) = ((s>>2)&7) ^ ((s>>5)&7); then transposed sigma-permuted store.
#pragma unroll
        for (int j = 0; j < 4; j++) {
            int c = wc * 64 + j * 16 + lr;
            float bv = bias[nb + c];
            int cw = c & 7, cg = c >> 3;
#pragma unroll
            for (int i = 0; i < 8; i++) {
#pragma unroll
                for (int r = 0; r < 4; r++) {
                    int s = wr * 128 + (i >> 2) * 64 + (i & 3) * 16 + lg * 4 + r;
                    int vs = ((s >> 2) & 7) ^ ((s >> 5) & 7);
                    smem[s * 256 + (((cg ^ vs) << 3) | cw)] = f2bf(acc[i][j][r] + bv);
                }
            }
        }
        __syncthreads();
#pragma unroll
        for (int k = 0; k < 16; k++) {
            int g = t + k * 512;                 // granule = (local col, s-32-group, octet)
            int lc = g >> 5;                     // local col 0..255
            int sgrp = (g >> 2) & 7, oct = g & 3;
            int cg = lc >> 3, cw = lc & 7;
            short tmp[8];
#pragma unroll
            for (int q = 0; q < 8; q++) {
                // Vt position p = oct*8+q holds key sigma(p) = (q>>2)*16 + oct*4 + (q&3)
                int key = oct * 4 + (q & 3) + ((q >> 2) << 4);
                int sl = sgrp * 32 + key;
                int vs = (key >> 2) ^ sgrp;      // == ((sl>>2)&7) ^ ((sl>>5)&7)
                tmp[q] = smem[sl * 256 + (((cg ^ vs) << 3) | cw)];
            }
            int vcol = nloc + lc;
            int hh = vcol / 80, dl = vcol - hh * 80;
            *reinterpret_cast<int4*>(
                &Vt[(size_t)(hh * HD + dl) * S_LEN + mb + sgrp * 32 + oct * 8]) =
                *reinterpret_cast<int4*>(tmp);
        }
    }
#undef AS_
#undef BS_
}

// ---------------- GEMM2: 128^2 2-phase (proj, +bias+residual, f32 out) -------------
// 1D grid 320 blocks, XCD-aware bijective swizzle (320 % 8 == 0).
__global__ __launch_bounds__(256) void gemm_bt_k(
    const short* __restrict__ A, const short* __restrict__ B, const float* __restrict__ bias,
    const float* __restrict__ resid, float* __restrict__ Out) {
    const int K = E_DIM;
    __shared__ short As[2][128 * 64];
    __shared__ short Bs[2][128 * 64];
    int t = threadIdx.x;
    int lane = t & 63, w = t >> 6;
    int wr = w >> 1, wc = w & 1;
    int lr = lane & 15, lg = lane >> 4;
    int bid = blockIdx.x;
    int swz = (bid & 7) * 40 + (bid >> 3);   // bijective over 320
    int mb = (swz / 10) * 128, nb = (swz % 10) * 128;

    const short* asrc[4];
    const short* bsrc[4];
#pragma unroll
    for (int c = 0; c < 4; c++) {
        int p = c * 256 + t;
        int m = p >> 3;
        int kg = (p & 7) ^ (m & 7);
        asrc[c] = A + (size_t)(mb + m) * K + kg * 8;
        bsrc[c] = B + (size_t)(nb + m) * K + kg * 8;
    }
    int xa = lr & 7;
    int cx0 = ((0 * 4 + lg) ^ xa) * 8;
    int cx1 = ((1 * 4 + lg) ^ xa) * 8;
    int rowA[4], rowB[4];
#pragma unroll
    for (int i = 0; i < 4; i++) {
        rowA[i] = (wr * 64 + i * 16 + lr) * 64;
        rowB[i] = (wc * 64 + i * 16 + lr) * 64;
    }

    f32x4 acc[4][4];
#pragma unroll
    for (int i = 0; i < 4; i++)
#pragma unroll
        for (int j = 0; j < 4; j++) acc[i][j] = (f32x4){0.f, 0.f, 0.f, 0.f};

#define G_STAGE(buf, kb)                                             \
    {                                                                \
        _Pragma("unroll") for (int c = 0; c < 4; c++) {              \
            int ldso = c * 2048 + w * 512;                           \
            gload16(asrc[c] + (kb), &As[buf][ldso]);                 \
            gload16(bsrc[c] + (kb), &Bs[buf][ldso]);                 \
        }                                                            \
    }

    G_STAGE(0, 0);
    asm volatile("s_waitcnt vmcnt(0)" ::: "memory");
    __syncthreads();

    int buf = 0;
    for (int kb = 0; kb < K; kb += 64) {
        if (kb + 64 < K) G_STAGE(buf ^ 1, kb + 64);
        __builtin_amdgcn_s_setprio(1);
#pragma unroll
        for (int kk = 0; kk < 2; kk++) {
            int cx = kk ? cx1 : cx0;
            bf16x8 af[4], bfr[4];
#pragma unroll
            for (int i = 0; i < 4; i++) {
                af[i] = ldb(&As[buf][rowA[i] + cx]);
                bfr[i] = ldb(&Bs[buf][rowB[i] + cx]);
            }
#pragma unroll
            for (int i = 0; i < 4; i++)
#pragma unroll
                for (int j = 0; j < 4; j++)
                    acc[i][j] = __builtin_amdgcn_mfma_f32_16x16x32_bf16(af[i], bfr[j], acc[i][j], 0, 0, 0);
        }
        __builtin_amdgcn_s_setprio(0);
        __syncthreads();
        buf ^= 1;
    }
#undef G_STAGE

#pragma unroll
    for (int j = 0; j < 4; j++) {
        int n = nb + wc * 64 + j * 16 + lr;
        float bv = bias[n];
#pragma unroll
        for (int i = 0; i < 4; i++) {
#pragma unroll
            for (int r = 0; r < 4; r++) {
                int s = mb + wr * 64 + i * 16 + lg * 4 + r;
                Out[s * E_DIM + n] = acc[i][j][r] + bv + resid[s * E_DIM + n];
            }
        }
    }
}

// ---------------- flash attention v9: split-K pairs, in-register P, V from L2 ------
// grid 512 blocks 1D (XCD remap: h = 2*(L&7) | (L>>8)); 512 thr = 8 waves.
// Wave pair i = w>>1 owns 32 q-rows; half = w&1 owns keys [32*half, +32) per tile.
// Static softmax (p = exp2(s) raw); P packed straight into the PV A-fragment via
// cvt_pk (V rows sigma-permuted in Vt).
// V fragments load DIRECTLY from global Vt (L2-resident per XCD; issued a full
// QK+softmax ahead of PV use; compiler-managed waits, no sync-structure change).
// Only K is LDS-staged: Ks 2x[64x104] = 26.6 KB; smem sized 41,472 B for the
// epilogue f32 scratch (Osc 40,960 + lsc 512).
__global__ __launch_bounds__(512, 4) void attn_k(const short* __restrict__ Qg,
                                                 const short* __restrict__ Kg,
                                                 const short* __restrict__ Vt,
                                                 short* __restrict__ Ob) {
    __shared__ __align__(16) short smem[20736];   // 41,472 B
    short* ksb = smem;                            // 2 bufs x 6656 shorts

    int t = threadIdx.x;
    int lane = t & 63, w = t >> 6;
    int lr = lane & 15, lg = lane >> 4;
    int pairi = w >> 1, half = w & 1;
    int L = blockIdx.x;
    int h = ((L & 7) << 1) | (L >> 8);
    int qb = ((L >> 3) & 31) << 7;

    const short* kgp = Kg + (size_t)h * S_LEN * HDP;
    const short* vgp = Vt + (size_t)h * HD * S_LEN;

    // Q fragments (B operand of swapped QK^T): 2 q-subtiles of the pair's 32 rows
    bf16x8 qf[2][3];
#pragma unroll
    for (int qq = 0; qq < 2; qq++) {
        const short* qp = Qg + ((size_t)h * S_LEN + qb + pairi * 32 + qq * 16 + lr) * HDP;
#pragma unroll
        for (int kk = 0; kk < 3; kk++) qf[qq][kk] = ldb(qp + kk * 32 + lg * 8);
    }
    f32x4 o[2][5];
#pragma unroll
    for (int qq = 0; qq < 2; qq++)
#pragma unroll
        for (int nd = 0; nd < 5; nd++) o[qq][nd] = (f32x4){0.f, 0.f, 0.f, 0.f};
    f32x4 l4[2] = {(f32x4){0.f, 0.f, 0.f, 0.f}, (f32x4){0.f, 0.f, 0.f, 0.f}};

    // per-lane V base pointers (PV B-fragments, direct global): row nd*16+lr,
    // cols half*32 + lg*8 + kb (sigma-permuted layout baked into Vt)
    const short* vbase[5];
#pragma unroll
    for (int nd = 0; nd < 5; nd++)
        vbase[nd] = vgp + (size_t)(nd * 16 + lr) * S_LEN + half * 32 + lg * 8;

    // per-lane K staging sources (pad granules reload row starts; advance per tile)
    int gk0 = t, rk0 = gk0 / 13, ok0 = gk0 % 13;
    if (ok0 == 12) ok0 = 0;
    const short* ksrc0 = kgp + rk0 * HDP + ok0 * 8;
    int gk1 = t + 512, rk1 = gk1 / 13, ok1 = gk1 % 13;
    if (ok1 == 12) ok1 = 0;
    const short* ksrc1 = kgp + rk1 * HDP + ok1 * 8;   // threads 0..319 (832 granules)

#define A_STAGE(buf, kb)                                                          \
    {                                                                             \
        gload16(ksrc0 + (size_t)(kb) * HDP, ksb + (buf)*6656 + w * 512);          \
        if (w < 5) gload16(ksrc1 + (size_t)(kb) * HDP, ksb + (buf)*6656 + 4096 + w * 512); \
    }

    A_STAGE(0, 0);
    asm volatile("s_waitcnt vmcnt(0)" ::: "memory");
    __syncthreads();

    int buf = 0;
    for (int kb = 0; kb < S_LEN; kb += 64) {
        if (kb + 64 < S_LEN) A_STAGE(buf ^ 1, kb + 64);
        const short* ks = ksb + buf * 6656;

        // ---- issue V loads early (global, per-wave private; hidden under QK) ----
        bf16x8 vf[5];
#pragma unroll
        for (int nd = 0; nd < 5; nd++) vf[nd] = ldb(vbase[nd] + kb);

        // ---- QK^T (swapped): sc[qq][n] = keys half*32 + n*16 + lg*4 + r, q = lr ----
        f32x4 sc[2][2];
#pragma unroll
        for (int qq = 0; qq < 2; qq++)
#pragma unroll
            for (int n = 0; n < 2; n++) sc[qq][n] = (f32x4){0.f, 0.f, 0.f, 0.f};
        __builtin_amdgcn_s_setprio(1);
#pragma unroll
        for (int n = 0; n < 2; n++) {
#pragma unroll
            for (int kk = 0; kk < 3; kk++) {
                bf16x8 kf = ldb(&ks[(half * 32 + n * 16 + lr) * 104 + kk * 32 + lg * 8]);
                sc[0][n] = __builtin_amdgcn_mfma_f32_16x16x32_bf16(kf, qf[0][kk], sc[0][n], 0, 0, 0);
                sc[1][n] = __builtin_amdgcn_mfma_f32_16x16x32_bf16(kf, qf[1][kk], sc[1][n], 0, 0, 0);
            }
        }
        __builtin_amdgcn_s_setprio(0);

        // ---- static softmax: p = exp2(s); pack straight into PV A-fragments ----
        bf16x8 pa[2];
#pragma unroll
        for (int qq = 0; qq < 2; qq++) {
#pragma unroll
            for (int n = 0; n < 2; n++) {
#pragma unroll
                for (int r = 0; r < 4; r++) sc[qq][n][r] = __builtin_amdgcn_exp2f(sc[qq][n][r]);
                l4[qq] += sc[qq][n];
            }
            uint4 pw;
            pw.x = cvt_pk_bf16(sc[qq][0][0], sc[qq][0][1]);
            pw.y = cvt_pk_bf16(sc[qq][0][2], sc[qq][0][3]);
            pw.z = cvt_pk_bf16(sc[qq][1][0], sc[qq][1][1]);
            pw.w = cvt_pk_bf16(sc[qq][1][2], sc[qq][1][3]);
            pa[qq] = __builtin_bit_cast(bf16x8, pw);
        }

        // ---- PV: O[qq][d] += P[qq][own keys] x V[sigma-permuted own keys][d] ----
        __builtin_amdgcn_s_setprio(1);
#pragma unroll
        for (int nd = 0; nd < 5; nd++) {
            o[0][nd] = __builtin_amdgcn_mfma_f32_16x16x32_bf16(pa[0], vf[nd], o[0][nd], 0, 0, 0);
            o[1][nd] = __builtin_amdgcn_mfma_f32_16x16x32_bf16(pa[1], vf[nd], o[1][nd], 0, 0, 0);
        }
        __builtin_amdgcn_s_setprio(0);

        __syncthreads();   // drains vmcnt (K stage) + lgkm; swap buffers
        buf ^= 1;
    }
#undef A_STAGE

    // ---- epilogue: combine wave pairs (exact sum: static softmax), normalize ----
    float lh[2];
#pragma unroll
    for (int qq = 0; qq < 2; qq++) {
        float l = l4[qq][0] + l4[qq][1] + l4[qq][2] + l4[qq][3];
        l += __shfl_xor(l, 16);
        l += __shfl_xor(l, 32);
        lh[qq] = l;   // half-sum for q = qq*16 + lr, valid on all lanes
    }
    // reuse LDS as f32 scratch: Osc[4][32][80] (40,960 B) + lsc[4][32] (512 B)
    float* Osc = reinterpret_cast<float*>(smem);
    float* lsc = reinterpret_cast<float*>(smem) + 10240;
    if (half) {
#pragma unroll
        for (int qq = 0; qq < 2; qq++) {
#pragma unroll
            for (int nd = 0; nd < 5; nd++)
#pragma unroll
                for (int r = 0; r < 4; r++)
                    Osc[(pairi * 32 + qq * 16 + lg * 4 + r) * 80 + nd * 16 + lr] = o[qq][nd][r];
            if (lg == 0) lsc[pairi * 32 + qq * 16 + lr] = lh[qq];
        }
    }
    __syncthreads();
    if (!half) {
        float rl[2][4];
#pragma unroll
        for (int qq = 0; qq < 2; qq++) {
            float lt = lh[qq] + lsc[pairi * 32 + qq * 16 + lr];
#pragma unroll
            for (int r = 0; r < 4; r++) {
                float lf = __shfl(lt, lg * 4 + r);
                rl[qq][r] = __builtin_amdgcn_rcpf(lf);
            }
        }
#pragma unroll
        for (int qq = 0; qq < 2; qq++)
#pragma unroll
            for (int nd = 0; nd < 5; nd++)
#pragma unroll
                for (int r = 0; r < 4; r++) {
                    int s = qb + pairi * 32 + qq * 16 + lg * 4 + r;
                    float val = o[qq][nd][r] + Osc[(pairi * 32 + qq * 16 + lg * 4 + r) * 80 + nd * 16 + lr];
                    Ob[s * E_DIM + h * HD + nd * 16 + lr] = f2bf(val * rl[qq][r]);
                }
    }
}

extern "C" void kernel_launch(void* const* d_in, const int* in_sizes, int n_in,
                              void* d_out, int out_size, void* d_ws, size_t ws_size,
                              hipStream_t stream) {
    const float* hidden = (const float*)d_in[0];
    const float* cosp = (const float*)d_in[1];
    const float* sinp = (const float*)d_in[2];
    const float* wqkv = (const float*)d_in[3];
    const float* bqkv = (const float*)d_in[4];
    const float* wproj = (const float*)d_in[5];
    const float* bproj = (const float*)d_in[6];
    float* out = (float*)d_out;

    char* p = (char*)d_ws;
    short* Xb = (short*)p;      p += (size_t)S_LEN * E_DIM * 2;       // also reused as Ob
    short* Wqkvb = (short*)p;   p += (size_t)3 * E_DIM * E_DIM * 2;
    short* Wprojb = (short*)p;  p += (size_t)E_DIM * E_DIM * 2;
    short* Qg = (short*)p;      p += (size_t)NH * S_LEN * HDP * 2;
    short* Kg = (short*)p;      p += (size_t)NH * S_LEN * HDP * 2;
    short* Vt = (short*)p;      p += (size_t)NH * HD * S_LEN * 2;
    short* Ob = Xb;

    const int na4 = S_LEN * E_DIM / 4;            // 1310720
    const int nb4 = 3 * E_DIM * E_DIM / 4;        // 1228800
    const int nc4 = E_DIM * E_DIM / 4;            // 409600
    const int nd4 = 2 * NH * S_LEN * 2;           // 262144 pad granules (Qg+Kg)
    cast3_k<<<(na4 + nb4 + nc4 + nd4 + 255) / 256, 256, 0, stream>>>(
        hidden, Xb, na4, wqkv, Wqkvb, nb4, wproj, Wprojb, nc4, Qg, Kg, nd4);

    gemm1_256_k<<<dim3(240), 512, 0, stream>>>(Xb, Wqkvb, bqkv, cosp, sinp, Qg, Kg, Vt);

    attn_k<<<dim3(512), 512, 0, stream>>>(Qg, Kg, Vt, Ob);

    gemm_bt_k<<<dim3(320), 256, 0, stream>>>(Ob, Wprojb, bproj, hidden, out);
}

// Round 17
// 176.248 us; speedup vs baseline: 1.3844x; 1.3844x over previous
//
#include <hip/hip_runtime.h>
#include <hip/hip_bf16.h>

// VisionAttention: S=4096, E=1280, H=16, D=80 (padded to 96 for MFMA K-steps)
// cast3->bf16 (Wqkv Q/K rows pair-interleaved; zero Qg/Kg pads) |
// GEMM1 qkv 256^2 8-phase (+bias, LDS bounce; Q/K readback applies RoPE -> Qg/Kg
// [H][S][96]; V readback transposes straight to Vt [H][80][S], sigma-permuted) |
// flash attention (split-K pairs, in-register P) | GEMM2 (+bias+residual, XCD swizzle)

#define S_LEN 4096
#define E_DIM 1280
#define NH 16
#define HD 80
#define HDP 96

typedef __bf16 bf16x8 __attribute__((ext_vector_type(8)));
typedef float f32x4 __attribute__((ext_vector_type(4)));

__device__ __forceinline__ short f2bf(float x) {
    __hip_bfloat16 h = __float2bfloat16(x);
    return __builtin_bit_cast(short, h);
}
__device__ __forceinline__ float bf2f(short x) {
    return __bfloat162float(__builtin_bit_cast(__hip_bfloat16, x));
}
__device__ __forceinline__ bf16x8 ldb(const short* p) {
    return *reinterpret_cast<const bf16x8*>(p);
}
// packed f32x2 -> bf16x2 (RNE), single VALU instr
__device__ __forceinline__ unsigned cvt_pk_bf16(float a, float b) {
    unsigned r;
    asm("v_cvt_pk_bf16_f32 %0, %1, %2" : "=v"(r) : "v"(a), "v"(b));
    return r;
}
// async global->LDS, 16B per lane; LDS dest = uniform base + lane*16
__device__ __forceinline__ void gload16(const void* g, void* l) {
    __builtin_amdgcn_global_load_lds(
        (const __attribute__((address_space(1))) unsigned int*)g,
        (__attribute__((address_space(3))) unsigned int*)l, 16, 0, 0);
}

// ---------------- fused cast f32 -> bf16 + pad-zero (4 segments, one launch) -------
__global__ __launch_bounds__(256) void cast3_k(const float* __restrict__ a, short* __restrict__ oa, int na4,
                                               const float* __restrict__ b, short* __restrict__ ob, int nb4,
                                               const float* __restrict__ c, short* __restrict__ oc, int nc4,
                                               short* __restrict__ Qg, short* __restrict__ Kg, int nd4) {
    int j = blockIdx.x * 256 + threadIdx.x;
    const float* src;
    short* dst;
    bool remap = false;
    if (j < na4) {
        src = a; dst = oa;
    } else {
        j -= na4;
        if (j < nb4) {
            src = b; dst = ob; remap = true;
        } else {
            j -= nb4;
            if (j < nc4) {
                src = c; dst = oc;
            } else {
                j -= nc4;
                if (j >= nd4) return;
                // pad-zero segment: nd4 = 2 * H*S*2 granules of 8 shorts
                int half = nd4 >> 1;
                short* base = (j < half) ? Qg : Kg;
                int rem = (j < half) ? j : j - half;
                int hs = rem >> 1, gp = rem & 1;
                int4 z = {0, 0, 0, 0};
                *reinterpret_cast<int4*>(&base[(size_t)hs * HDP + 80 + gp * 8]) = z;
                return;
            }
        }
    }
    float4 v = *reinterpret_cast<const float4*>(&src[j * 4]);
    int dj = j;
    if (remap) {
        int row = j / 320, c4 = j - row * 320;   // 320 float4-chunks per 1280-col row
        if (row < 2560) {                        // Q,K parts only
            int part = row / 1280;
            int loc = row - part * 1280;
            int hh = loc / 80, d = loc - hh * 80;
            int dp = (d < 40) ? 2 * d : 2 * (d - 40) + 1;
            dj = (part * 1280 + hh * 80 + dp) * 320 + c4;
        }
    }
    ushort4 o;
    o.x = (unsigned short)f2bf(v.x);
    o.y = (unsigned short)f2bf(v.y);
    o.z = (unsigned short)f2bf(v.z);
    o.w = (unsigned short)f2bf(v.w);
    *reinterpret_cast<ushort4*>(&dst[dj * 4]) = o;
}

// ---------------- GEMM1: 256x256 tile, BK=64, 8-phase counted-vmcnt ----------------
// C = A * B^T. Epilogue via bank-swizzled LDS bounce [256][256]:
//  Q/K parts: readback granule (4 RoPE pairs) -> RoPE + (Q) scale -> Qg/Kg [H][S][96]
//  V part:    column readback -> sigma-permuted transposed store to Vt [H][80][S]
__global__ __launch_bounds__(512, 2) void gemm1_256_k(
    const short* __restrict__ A, const short* __restrict__ B, const float* __restrict__ bias,
    const float* __restrict__ cosp, const float* __restrict__ sinp,
    short* __restrict__ Qg, short* __restrict__ Kg, short* __restrict__ Vt) {
    const int K = E_DIM;
    __shared__ __align__(16) short smem[65536];   // 128 KB: As | Bs, reused as bounce
#define AS_(d, kh) (smem + (d)*16384 + (kh)*8192)
#define BS_(d, kh) (smem + 32768 + (d)*16384 + (kh)*8192)
    int t = threadIdx.x;
    int lane = t & 63, w = t >> 6;
    int wr = w >> 2, wc = w & 3;
    int lr = lane & 15, lg = lane >> 4;
    int bid = blockIdx.x;
    int swz = (bid & 7) * 30 + (bid >> 3);   // 240 blocks, 240%8==0 -> bijective
    int bm = swz / 15, bn = swz % 15;
    int mb = bm * 256, nb = bn * 256;

    // staging sources: dest granule p (row=p>>2, phys=p&3) <- logical (p&3)^((p>>3)&3)
    int lgs = (t & 3) ^ ((t >> 3) & 3);
    const short* aS = A + (size_t)(mb + (t >> 2)) * K + lgs * 8;
    const short* bS = B + (size_t)(nb + (t >> 2)) * K + lgs * 8;
    const int rowStep = 128 * K;   // second load: rows +128

    // frag offsets: row r, granule lg -> r*32 + (lg ^ ((r>>1)&3))*8
    int aoff[2][4], boff[4];
#pragma unroll
    for (int mq = 0; mq < 2; mq++)
#pragma unroll
        for (int ii = 0; ii < 4; ii++) {
            int r = wr * 128 + mq * 64 + ii * 16 + lr;
            aoff[mq][ii] = r * 32 + ((lg ^ ((r >> 1) & 3)) * 8);
        }
#pragma unroll
    for (int n = 0; n < 4; n++) {
        int r = wc * 64 + n * 16 + lr;
        boff[n] = r * 32 + ((lg ^ ((r >> 1) & 3)) * 8);
    }

    f32x4 acc[8][4];
#pragma unroll
    for (int i = 0; i < 8; i++)
#pragma unroll
        for (int n = 0; n < 4; n++) acc[i][n] = (f32x4){0.f, 0.f, 0.f, 0.f};

#define STG_A(d, kh, kb2)                                              \
    {                                                                  \
        gload16(aS + (kb2) + (kh)*32, AS_(d, kh) + w * 512);           \
        gload16(aS + rowStep + (kb2) + (kh)*32, AS_(d, kh) + 4096 + w * 512); \
    }
#define STG_B(d, kh, kb2)                                              \
    {                                                                  \
        gload16(bS + (kb2) + (kh)*32, BS_(d, kh) + w * 512);           \
        gload16(bS + rowStep + (kb2) + (kh)*32, BS_(d, kh) + 4096 + w * 512); \
    }

    // prologue: tile 0, all 4 half-tiles; wait A0,B0 only
    STG_A(0, 0, 0);
    STG_B(0, 0, 0);
    STG_A(0, 1, 0);
    STG_B(0, 1, 0);
    asm volatile("s_waitcnt vmcnt(4)" ::: "memory");
    __builtin_amdgcn_s_barrier();
    asm volatile("" ::: "memory");

    for (int kb = 0; kb < K; kb += 64) {
        int d = (kb >> 6) & 1;
        int kb2 = kb + 64;
        bool more = kb2 < K;
        bf16x8 af[4], bfr[4];

        // ---- phase 1: K-half 0, M-quad 0 (8 ds_reads; stage next A0) ----
#pragma unroll
        for (int n = 0; n < 4; n++) bfr[n] = ldb(&BS_(d, 0)[boff[n]]);
#pragma unroll
        for (int ii = 0; ii < 4; ii++) af[ii] = ldb(&AS_(d, 0)[aoff[0][ii]]);
        if (more) STG_A(d ^ 1, 0, kb2);
        __builtin_amdgcn_s_barrier();
        asm volatile("s_waitcnt lgkmcnt(0)" ::: "memory");
        __builtin_amdgcn_sched_barrier(0);
        __builtin_amdgcn_s_setprio(1);
#pragma unroll
        for (int ii = 0; ii < 4; ii++)
#pragma unroll
            for (int n = 0; n < 4; n++)
                acc[ii][n] = __builtin_amdgcn_mfma_f32_16x16x32_bf16(af[ii], bfr[n], acc[ii][n], 0, 0, 0);
        __builtin_amdgcn_s_setprio(0);
        __builtin_amdgcn_s_barrier();
        asm volatile("" ::: "memory");

        // ---- phase 2: K-half 0, M-quad 1 (4 ds_reads; stage next B0; vmcnt) ----
#pragma unroll
        for (int ii = 0; ii < 4; ii++) af[ii] = ldb(&AS_(d, 0)[aoff[1][ii]]);
        if (more) {
            STG_B(d ^ 1, 0, kb2);
            asm volatile("s_waitcnt vmcnt(4)" ::: "memory");   // drain this tile's A1,B1
        } else {
            asm volatile("s_waitcnt vmcnt(0)" ::: "memory");
        }
        __builtin_amdgcn_s_barrier();
        asm volatile("s_waitcnt lgkmcnt(0)" ::: "memory");
        __builtin_amdgcn_sched_barrier(0);
        __builtin_amdgcn_s_setprio(1);
#pragma unroll
        for (int ii = 0; ii < 4; ii++)
#pragma unroll
            for (int n = 0; n < 4; n++)
                acc[4 + ii][n] = __builtin_amdgcn_mfma_f32_16x16x32_bf16(af[ii], bfr[n], acc[4 + ii][n], 0, 0, 0);
        __builtin_amdgcn_s_setprio(0);
        __builtin_amdgcn_s_barrier();
        asm volatile("" ::: "memory");

        // ---- phase 3: K-half 1, M-quad 0 (8 ds_reads; stage next A1) ----
#pragma unroll
        for (int n = 0; n < 4; n++) bfr[n] = ldb(&BS_(d, 1)[boff[n]]);
#pragma unroll
        for (int ii = 0; ii < 4; ii++) af[ii] = ldb(&AS_(d, 1)[aoff[0][ii]]);
        if (more) STG_A(d ^ 1, 1, kb2);
        __builtin_amdgcn_s_barrier();
        asm volatile("s_waitcnt lgkmcnt(0)" ::: "memory");
        __builtin_amdgcn_sched_barrier(0);
        __builtin_amdgcn_s_setprio(1);
#pragma unroll
        for (int ii = 0; ii < 4; ii++)
#pragma unroll
            for (int n = 0; n < 4; n++)
                acc[ii][n] = __builtin_amdgcn_mfma_f32_16x16x32_bf16(af[ii], bfr[n], acc[ii][n], 0, 0, 0);
        __builtin_amdgcn_s_setprio(0);
        __builtin_amdgcn_s_barrier();
        asm volatile("" ::: "memory");

        // ---- phase 4: K-half 1, M-quad 1 (4 ds_reads; stage next B1; vmcnt) ----
#pragma unroll
        for (int ii = 0; ii < 4; ii++) af[ii] = ldb(&AS_(d, 1)[aoff[1][ii]]);
        if (more) {
            STG_B(d ^ 1, 1, kb2);
            asm volatile("s_waitcnt vmcnt(4)" ::: "memory");   // drain next tile's A0,B0
        }
        __builtin_amdgcn_s_barrier();
        asm volatile("s_waitcnt lgkmcnt(0)" ::: "memory");
        __builtin_amdgcn_sched_barrier(0);
        __builtin_amdgcn_s_setprio(1);
#pragma unroll
        for (int ii = 0; ii < 4; ii++)
#pragma unroll
            for (int n = 0; n < 4; n++)
                acc[4 + ii][n] = __builtin_amdgcn_mfma_f32_16x16x32_bf16(af[ii], bfr[n], acc[4 + ii][n], 0, 0, 0);
        __builtin_amdgcn_s_setprio(0);
        __builtin_amdgcn_s_barrier();
        asm volatile("" ::: "memory");
    }
#undef STG_A
#undef STG_B

    // ---- epilogue: bias -> bank-swizzled LDS bounce -> readback ----
    int part = nb / E_DIM;   // tile never crosses q/k/v boundary (1280 % 256 == 0)
    int nloc = nb - part * E_DIM;
    if (part < 2) {
        // write with row-read-friendly swizzle: granule cg -> cg ^ ((s>>2)&3)
#pragma unroll
        for (int j = 0; j < 4; j++) {
            int c = wc * 64 + j * 16 + lr;
            int pcol = nloc + c;
            int hh = pcol / 80, dl = pcol - hh * 80;
            float bv = bias[part * E_DIM + hh * 80 + ((dl & 1) ? (dl >> 1) + 40 : (dl >> 1))];
            int cw = c & 7, cg = c >> 3;
#pragma unroll
            for (int i = 0; i < 8; i++) {
#pragma unroll
                for (int r = 0; r < 4; r++) {
                    int s = wr * 128 + (i >> 2) * 64 + (i & 3) * 16 + lg * 4 + r;
                    smem[s * 256 + (((cg ^ ((s >> 2) & 3)) << 3) | cw)] = f2bf(acc[i][j][r] + bv);
                }
            }
        }
        __syncthreads();
        short* dst = part ? Kg : Qg;
        const float qs = part ? 1.0f : 0.16129849190f;   // log2(e)/sqrt(80) on Q
#pragma unroll
        for (int k = 0; k < 16; k++) {
            int g = t + k * 512;                 // 8192 granules of 16B
            int row = g >> 5, gc = g & 31;
            int pg = gc ^ ((row >> 2) & 3);
            int4 v = *reinterpret_cast<const int4*>(&smem[row * 256 + pg * 8]);
            int s = mb + row;
            int pcol = nloc + gc * 8;            // granule never crosses a head (80%8==0)
            int hh = pcol / 80;
            int dl = pcol - hh * 80;             // multiple of 8
            int i2 = dl >> 1;                    // multiple of 4
            float4 cs = *reinterpret_cast<const float4*>(&cosp[s * HD + i2]);
            float4 sn = *reinterpret_cast<const float4*>(&sinp[s * HD + i2]);
            const short* sp = reinterpret_cast<const short*>(&v);
            float f[8];
#pragma unroll
            for (int i = 0; i < 8; i++) f[i] = bf2f(sp[i]);
            float c0 = cs.x * qs, s0 = sn.x * qs;
            float c1 = cs.y * qs, s1 = sn.y * qs;
            float c2 = cs.z * qs, s2 = sn.z * qs;
            float c3 = cs.w * qs, s3 = sn.w * qs;
            uint4 pw;
            pw.x = cvt_pk_bf16(f[0] * c0 - f[1] * s0, f[1] * c0 + f[0] * s0);
            pw.y = cvt_pk_bf16(f[2] * c1 - f[3] * s1, f[3] * c1 + f[2] * s1);
            pw.z = cvt_pk_bf16(f[4] * c2 - f[5] * s2, f[5] * c2 + f[4] * s2);
            pw.w = cvt_pk_bf16(f[6] * c3 - f[7] * s3, f[7] * c3 + f[6] * s3);
            *reinterpret_cast<uint4*>(&dst[((size_t)hh * S_LEN + s) * HDP + dl]) = pw;
        }
    } else {
        // V: write with column-read-friendly swizzle: granule cg -> cg ^ vswz(s),
        // vswz(s) = ((s>>2)&7) ^ ((s>>5)&7); then transposed sigma-permuted store.
#pragma unroll
        for (int j = 0; j < 4; j++) {
            int c = wc * 64 + j * 16 + lr;
            float bv = bias[nb + c];
            int cw = c & 7, cg = c >> 3;
#pragma unroll
            for (int i = 0; i < 8; i++) {
#pragma unroll
                for (int r = 0; r < 4; r++) {
                    int s = wr * 128 + (i >> 2) * 64 + (i & 3) * 16 + lg * 4 + r;
                    int vs = ((s >> 2) & 7) ^ ((s >> 5) & 7);
                    smem[s * 256 + (((cg ^ vs) << 3) | cw)] = f2bf(acc[i][j][r] + bv);
                }
            }
        }
        __syncthreads();
#pragma unroll
        for (int k = 0; k < 16; k++) {
            int g = t + k * 512;                 // granule = (local col, s-32-group, octet)
            int lc = g >> 5;                     // local col 0..255
            int sgrp = (g >> 2) & 7, oct = g & 3;
            int cg = lc >> 3, cw = lc & 7;
            short tmp[8];
#pragma unroll
            for (int q = 0; q < 8; q++) {
                // Vt position p = oct*8+q holds key sigma(p) = (q>>2)*16 + oct*4 + (q&3)
                int key = oct * 4 + (q & 3) + ((q >> 2) << 4);
                int sl = sgrp * 32 + key;
                int vs = (key >> 2) ^ sgrp;      // == ((sl>>2)&7) ^ ((sl>>5)&7)
                tmp[q] = smem[sl * 256 + (((cg ^ vs) << 3) | cw)];
            }
            int vcol = nloc + lc;
            int hh = vcol / 80, dl = vcol - hh * 80;
            *reinterpret_cast<int4*>(
                &Vt[(size_t)(hh * HD + dl) * S_LEN + mb + sgrp * 32 + oct * 8]) =
                *reinterpret_cast<int4*>(tmp);
        }
    }
#undef AS_
#undef BS_
}

// ---------------- GEMM2: 128^2 2-phase (proj, +bias+residual, f32 out) -------------
// 1D grid 320 blocks, XCD-aware bijective swizzle (320 % 8 == 0).
__global__ __launch_bounds__(256) void gemm_bt_k(
    const short* __restrict__ A, const short* __restrict__ B, const float* __restrict__ bias,
    const float* __restrict__ resid, float* __restrict__ Out) {
    const int K = E_DIM;
    __shared__ short As[2][128 * 64];
    __shared__ short Bs[2][128 * 64];
    int t = threadIdx.x;
    int lane = t & 63, w = t >> 6;
    int wr = w >> 1, wc = w & 1;
    int lr = lane & 15, lg = lane >> 4;
    int bid = blockIdx.x;
    int swz = (bid & 7) * 40 + (bid >> 3);   // bijective over 320
    int mb = (swz / 10) * 128, nb = (swz % 10) * 128;

    const short* asrc[4];
    const short* bsrc[4];
#pragma unroll
    for (int c = 0; c < 4; c++) {
        int p = c * 256 + t;
        int m = p >> 3;
        int kg = (p & 7) ^ (m & 7);
        asrc[c] = A + (size_t)(mb + m) * K + kg * 8;
        bsrc[c] = B + (size_t)(nb + m) * K + kg * 8;
    }
    int xa = lr & 7;
    int cx0 = ((0 * 4 + lg) ^ xa) * 8;
    int cx1 = ((1 * 4 + lg) ^ xa) * 8;
    int rowA[4], rowB[4];
#pragma unroll
    for (int i = 0; i < 4; i++) {
        rowA[i] = (wr * 64 + i * 16 + lr) * 64;
        rowB[i] = (wc * 64 + i * 16 + lr) * 64;
    }

    f32x4 acc[4][4];
#pragma unroll
    for (int i = 0; i < 4; i++)
#pragma unroll
        for (int j = 0; j < 4; j++) acc[i][j] = (f32x4){0.f, 0.f, 0.f, 0.f};

#define G_STAGE(buf, kb)                                             \
    {                                                                \
        _Pragma("unroll") for (int c = 0; c < 4; c++) {              \
            int ldso = c * 2048 + w * 512;                           \
            gload16(asrc[c] + (kb), &As[buf][ldso]);                 \
            gload16(bsrc[c] + (kb), &Bs[buf][ldso]);                 \
        }                                                            \
    }

    G_STAGE(0, 0);
    asm volatile("s_waitcnt vmcnt(0)" ::: "memory");
    __syncthreads();

    int buf = 0;
    for (int kb = 0; kb < K; kb += 64) {
        if (kb + 64 < K) G_STAGE(buf ^ 1, kb + 64);
        __builtin_amdgcn_s_setprio(1);
#pragma unroll
        for (int kk = 0; kk < 2; kk++) {
            int cx = kk ? cx1 : cx0;
            bf16x8 af[4], bfr[4];
#pragma unroll
            for (int i = 0; i < 4; i++) {
                af[i] = ldb(&As[buf][rowA[i] + cx]);
                bfr[i] = ldb(&Bs[buf][rowB[i] + cx]);
            }
#pragma unroll
            for (int i = 0; i < 4; i++)
#pragma unroll
                for (int j = 0; j < 4; j++)
                    acc[i][j] = __builtin_amdgcn_mfma_f32_16x16x32_bf16(af[i], bfr[j], acc[i][j], 0, 0, 0);
        }
        __builtin_amdgcn_s_setprio(0);
        __syncthreads();
        buf ^= 1;
    }
#undef G_STAGE

#pragma unroll
    for (int j = 0; j < 4; j++) {
        int n = nb + wc * 64 + j * 16 + lr;
        float bv = bias[n];
#pragma unroll
        for (int i = 0; i < 4; i++) {
#pragma unroll
            for (int r = 0; r < 4; r++) {
                int s = mb + wr * 64 + i * 16 + lg * 4 + r;
                Out[s * E_DIM + n] = acc[i][j][r] + bv + resid[s * E_DIM + n];
            }
        }
    }
}

// ---------------- flash attention v6: split-K pairs, in-register P ----------------
// grid 512 blocks 1D (XCD remap: h = 2*(L&7) | (L>>8)); 512 thr = 8 waves.
// Wave pair i = w>>1 owns 32 q-rows; half = w&1 owns keys [32*half, +32) per tile.
// Static softmax (p = exp2(s) raw); P packed straight into the PV A-fragment via
// cvt_pk (V rows sigma-permuted in Vt) — P never touches LDS.
// LDS 49664 B: Ks 2x[64x104] | Vs 2x[80x72]. Epilogue reuses LDS as f32 scratch.
__global__ __launch_bounds__(512, 4) void attn_k(const short* __restrict__ Qg,
                                                 const short* __restrict__ Kg,
                                                 const short* __restrict__ Vt,
                                                 short* __restrict__ Ob) {
    __shared__ __align__(16) short smem[24832];   // 49664 B
    short* ksb = smem;                            // 2 bufs x 6656 shorts
    short* vsb = smem + 13312;                    // 2 bufs x 5760 shorts

    int t = threadIdx.x;
    int lane = t & 63, w = t >> 6;
    int lr = lane & 15, lg = lane >> 4;
    int pairi = w >> 1, half = w & 1;
    int L = blockIdx.x;
    int h = ((L & 7) << 1) | (L >> 8);
    int qb = ((L >> 3) & 31) << 7;

    const short* kgp = Kg + (size_t)h * S_LEN * HDP;
    const short* vgp = Vt + (size_t)h * HD * S_LEN;

    // Q fragments (B operand of swapped QK^T): 2 q-subtiles of the pair's 32 rows
    bf16x8 qf[2][3];
#pragma unroll
    for (int qq = 0; qq < 2; qq++) {
        const short* qp = Qg + ((size_t)h * S_LEN + qb + pairi * 32 + qq * 16 + lr) * HDP;
#pragma unroll
        for (int kk = 0; kk < 3; kk++) qf[qq][kk] = ldb(qp + kk * 32 + lg * 8);
    }
    f32x4 o[2][5];
#pragma unroll
    for (int qq = 0; qq < 2; qq++)
#pragma unroll
        for (int nd = 0; nd < 5; nd++) o[qq][nd] = (f32x4){0.f, 0.f, 0.f, 0.f};
    f32x4 l4[2] = {(f32x4){0.f, 0.f, 0.f, 0.f}, (f32x4){0.f, 0.f, 0.f, 0.f}};

    // per-lane staging sources (pad granules reload row starts; advance per tile)
    int gk0 = t, rk0 = gk0 / 13, ok0 = gk0 % 13;
    if (ok0 == 12) ok0 = 0;
    const short* ksrc0 = kgp + rk0 * HDP + ok0 * 8;
    int gk1 = t + 512, rk1 = gk1 / 13, ok1 = gk1 % 13;
    if (ok1 == 12) ok1 = 0;
    const short* ksrc1 = kgp + rk1 * HDP + ok1 * 8;   // waves 0..4 (832 granules)
    int gv0 = t, rv0 = gv0 / 9, ov0 = gv0 % 9;
    if (ov0 == 8) ov0 = 0;
    const short* vsrc0 = vgp + (size_t)rv0 * S_LEN + ov0 * 8;
    bool v1v = (t + 512) < 720;
    int gv1 = t + 512, rv1 = gv1 / 9, ov1 = gv1 % 9;
    if (ov1 == 8) ov1 = 0;
    const short* vsrc1 = vgp + (size_t)rv1 * S_LEN + ov1 * 8;

#define A_STAGE(buf, kb)                                                          \
    {                                                                             \
        gload16(ksrc0 + (size_t)(kb) * HDP, ksb + (buf)*6656 + w * 512);          \
        if (w < 5) gload16(ksrc1 + (size_t)(kb) * HDP, ksb + (buf)*6656 + 4096 + w * 512); \
        gload16(vsrc0 + (kb), vsb + (buf)*5760 + w * 512);                        \
        if (v1v) gload16(vsrc1 + (kb), vsb + (buf)*5760 + 4096 + w * 512);        \
    }

    A_STAGE(0, 0);
    asm volatile("s_waitcnt vmcnt(0)" ::: "memory");
    __syncthreads();

    int buf = 0;
    for (int kb = 0; kb < S_LEN; kb += 64) {
        if (kb + 64 < S_LEN) A_STAGE(buf ^ 1, kb + 64);
        const short* ks = ksb + buf * 6656;
        const short* vs = vsb + buf * 5760;

        // ---- QK^T (swapped): sc[qq][n] = keys half*32 + n*16 + lg*4 + r, q = lr ----
        f32x4 sc[2][2];
#pragma unroll
        for (int qq = 0; qq < 2; qq++)
#pragma unroll
            for (int n = 0; n < 2; n++) sc[qq][n] = (f32x4){0.f, 0.f, 0.f, 0.f};
        __builtin_amdgcn_s_setprio(1);
#pragma unroll
        for (int n = 0; n < 2; n++) {
#pragma unroll
            for (int kk = 0; kk < 3; kk++) {
                bf16x8 kf = ldb(&ks[(half * 32 + n * 16 + lr) * 104 + kk * 32 + lg * 8]);
                sc[0][n] = __builtin_amdgcn_mfma_f32_16x16x32_bf16(kf, qf[0][kk], sc[0][n], 0, 0, 0);
                sc[1][n] = __builtin_amdgcn_mfma_f32_16x16x32_bf16(kf, qf[1][kk], sc[1][n], 0, 0, 0);
            }
        }
        __builtin_amdgcn_s_setprio(0);

        // ---- static softmax: p = exp2(s); pack straight into PV A-fragments ----
        bf16x8 pa[2];
#pragma unroll
        for (int qq = 0; qq < 2; qq++) {
#pragma unroll
            for (int n = 0; n < 2; n++) {
#pragma unroll
                for (int r = 0; r < 4; r++) sc[qq][n][r] = __builtin_amdgcn_exp2f(sc[qq][n][r]);
                l4[qq] += sc[qq][n];
            }
            uint4 pw;
            pw.x = cvt_pk_bf16(sc[qq][0][0], sc[qq][0][1]);
            pw.y = cvt_pk_bf16(sc[qq][0][2], sc[qq][0][3]);
            pw.z = cvt_pk_bf16(sc[qq][1][0], sc[qq][1][1]);
            pw.w = cvt_pk_bf16(sc[qq][1][2], sc[qq][1][3]);
            pa[qq] = __builtin_bit_cast(bf16x8, pw);
        }

        // ---- PV: O[qq][d] += P[qq][own keys] x V[sigma-permuted own keys][d] ----
        __builtin_amdgcn_s_setprio(1);
#pragma unroll
        for (int nd = 0; nd < 5; nd++) {
            bf16x8 vf = ldb(&vs[(nd * 16 + lr) * 72 + half * 32 + lg * 8]);
            o[0][nd] = __builtin_amdgcn_mfma_f32_16x16x32_bf16(pa[0], vf, o[0][nd], 0, 0, 0);
            o[1][nd] = __builtin_amdgcn_mfma_f32_16x16x32_bf16(pa[1], vf, o[1][nd], 0, 0, 0);
        }
        __builtin_amdgcn_s_setprio(0);

        __syncthreads();   // drains vmcnt (stage) + lgkm; swap buffers
        buf ^= 1;
    }
#undef A_STAGE

    // ---- epilogue: combine wave pairs (exact sum: static softmax), normalize ----
    float lh[2];
#pragma unroll
    for (int qq = 0; qq < 2; qq++) {
        float l = l4[qq][0] + l4[qq][1] + l4[qq][2] + l4[qq][3];
        l += __shfl_xor(l, 16);
        l += __shfl_xor(l, 32);
        lh[qq] = l;   // half-sum for q = qq*16 + lr, valid on all lanes
    }
    // reuse staging LDS as f32 scratch: Osc[4][32][80] + lsc[4][32]
    float* Osc = reinterpret_cast<float*>(smem);            // 40960 B
    float* lsc = reinterpret_cast<float*>(smem) + 10240;    // 512 B
    if (half) {
#pragma unroll
        for (int qq = 0; qq < 2; qq++) {
#pragma unroll
            for (int nd = 0; nd < 5; nd++)
#pragma unroll
                for (int r = 0; r < 4; r++)
                    Osc[(pairi * 32 + qq * 16 + lg * 4 + r) * 80 + nd * 16 + lr] = o[qq][nd][r];
            if (lg == 0) lsc[pairi * 32 + qq * 16 + lr] = lh[qq];
        }
    }
    __syncthreads();
    if (!half) {
        float rl[2][4];
#pragma unroll
        for (int qq = 0; qq < 2; qq++) {
            float lt = lh[qq] + lsc[pairi * 32 + qq * 16 + lr];
#pragma unroll
            for (int r = 0; r < 4; r++) {
                float lf = __shfl(lt, lg * 4 + r);
                rl[qq][r] = __builtin_amdgcn_rcpf(lf);
            }
        }
#pragma unroll
        for (int qq = 0; qq < 2; qq++)
#pragma unroll
            for (int nd = 0; nd < 5; nd++)
#pragma unroll
                for (int r = 0; r < 4; r++) {
                    int s = qb + pairi * 32 + qq * 16 + lg * 4 + r;
                    float val = o[qq][nd][r] + Osc[(pairi * 32 + qq * 16 + lg * 4 + r) * 80 + nd * 16 + lr];
                    Ob[s * E_DIM + h * HD + nd * 16 + lr] = f2bf(val * rl[qq][r]);
                }
    }
}

extern "C" void kernel_launch(void* const* d_in, const int* in_sizes, int n_in,
                              void* d_out, int out_size, void* d_ws, size_t ws_size,
                              hipStream_t stream) {
    const float* hidden = (const float*)d_in[0];
    const float* cosp = (const float*)d_in[1];
    const float* sinp = (const float*)d_in[2];
    const float* wqkv = (const float*)d_in[3];
    const float* bqkv = (const float*)d_in[4];
    const float* wproj = (const float*)d_in[5];
    const float* bproj = (const float*)d_in[6];
    float* out = (float*)d_out;

    char* p = (char*)d_ws;
    short* Xb = (short*)p;      p += (size_t)S_LEN * E_DIM * 2;       // also reused as Ob
    short* Wqkvb = (short*)p;   p += (size_t)3 * E_DIM * E_DIM * 2;
    short* Wprojb = (short*)p;  p += (size_t)E_DIM * E_DIM * 2;
    short* Qg = (short*)p;      p += (size_t)NH * S_LEN * HDP * 2;
    short* Kg = (short*)p;      p += (size_t)NH * S_LEN * HDP * 2;
    short* Vt = (short*)p;      p += (size_t)NH * HD * S_LEN * 2;
    short* Ob = Xb;

    const int na4 = S_LEN * E_DIM / 4;            // 1310720
    const int nb4 = 3 * E_DIM * E_DIM / 4;        // 1228800
    const int nc4 = E_DIM * E_DIM / 4;            // 409600
    const int nd4 = 2 * NH * S_LEN * 2;           // 262144 pad granules (Qg+Kg)
    cast3_k<<<(na4 + nb4 + nc4 + nd4 + 255) / 256, 256, 0, stream>>>(
        hidden, Xb, na4, wqkv, Wqkvb, nb4, wproj, Wprojb, nc4, Qg, Kg, nd4);

    gemm1_256_k<<<dim3(240), 512, 0, stream>>>(Xb, Wqkvb, bqkv, cosp, sinp, Qg, Kg, Vt);

    attn_k<<<dim3(512), 512, 0, stream>>>(Qg, Kg, Vt, Ob);

    gemm_bt_k<<<dim3(320), 256, 0, stream>>>(Ob, Wprojb, bproj, hidden, out);
}